// Round 1
// baseline (822.354 us; speedup 1.0000x reference)
//
#include <hip/hip_runtime.h>
#include <math.h>

#define B_    2048
#define S_    134
#define E_    256
#define H_    1024
#define T_    5
#define KK_   6
#define NROWS (B_*T_)          // 10240
#define R_    16               // rows per block
#define NBLK  (NROWS/R_)       // 640

// output layout (flat concat in return order)
#define OFF_LOGITS 1
#define OFF_SCORES (OFF_LOGITS + NROWS*12)   // 122881
#define OFF_SEL    (OFF_SCORES + NROWS*6)    // 184321
#define OFF_LPK    (OFF_SEL + NROWS*2)       // 204801

// One decoder phase: GEMM1 (x@w1+b1) -> LayerNorm -> ReLU -> GEMM2 ([x,h]@w2+b2)
// NOUT = 12 (logits decoder) or 6 (scores decoder)
template<int NOUT>
__device__ __forceinline__ void decoder_phase(
    const float* const* xrow,
    const float* __restrict__ w1, const float* __restrict__ b1,
    const float* __restrict__ ga, const float* __restrict__ be,
    const float* __restrict__ w2, const float* __restrict__ b2,
    float (*hs)[H_], float (*red)[4][2], float* mu_s, float* rs_s,
    float* osh, float* __restrict__ gout, int g0, int tid)
{
    const int wave = tid >> 6;
    const int lane = tid & 63;
    const int j0   = tid * 4;

    // ---- GEMM1: acc[r][i] = x[r] . w1[:, j0+i] ----
    float acc[R_][4];
#pragma unroll
    for (int r = 0; r < R_; ++r) {
        acc[r][0] = 0.f; acc[r][1] = 0.f; acc[r][2] = 0.f; acc[r][3] = 0.f;
    }

    for (int k0 = 0; k0 < E_; k0 += 4) {
        float4 wa = *(const float4*)(w1 + (size_t)(k0+0)*H_ + j0);
        float4 wb = *(const float4*)(w1 + (size_t)(k0+1)*H_ + j0);
        float4 wc = *(const float4*)(w1 + (size_t)(k0+2)*H_ + j0);
        float4 wd = *(const float4*)(w1 + (size_t)(k0+3)*H_ + j0);
#pragma unroll
        for (int r = 0; r < R_; ++r) {
            float4 xv = *(const float4*)(xrow[r] + k0);   // wave-uniform -> s_load
            acc[r][0] += xv.x*wa.x; acc[r][1] += xv.x*wa.y; acc[r][2] += xv.x*wa.z; acc[r][3] += xv.x*wa.w;
            acc[r][0] += xv.y*wb.x; acc[r][1] += xv.y*wb.y; acc[r][2] += xv.y*wb.z; acc[r][3] += xv.y*wb.w;
            acc[r][0] += xv.z*wc.x; acc[r][1] += xv.z*wc.y; acc[r][2] += xv.z*wc.z; acc[r][3] += xv.z*wc.w;
            acc[r][0] += xv.w*wd.x; acc[r][1] += xv.w*wd.y; acc[r][2] += xv.w*wd.z; acc[r][3] += xv.w*wd.w;
        }
    }

    // bias
    {
        float4 bv = *(const float4*)(b1 + j0);
#pragma unroll
        for (int r = 0; r < R_; ++r) {
            acc[r][0] += bv.x; acc[r][1] += bv.y; acc[r][2] += bv.z; acc[r][3] += bv.w;
        }
    }

    // ---- LayerNorm stats: per-row sum / sumsq across 1024 cols ----
#pragma unroll
    for (int r = 0; r < R_; ++r) {
        float s  = acc[r][0] + acc[r][1] + acc[r][2] + acc[r][3];
        float ss = acc[r][0]*acc[r][0] + acc[r][1]*acc[r][1]
                 + acc[r][2]*acc[r][2] + acc[r][3]*acc[r][3];
#pragma unroll
        for (int off = 32; off > 0; off >>= 1) {
            s  += __shfl_xor(s,  off, 64);
            ss += __shfl_xor(ss, off, 64);
        }
        if (lane == 0) { red[r][wave][0] = s; red[r][wave][1] = ss; }
    }
    __syncthreads();
    if (tid < R_) {
        float s  = red[tid][0][0] + red[tid][1][0] + red[tid][2][0] + red[tid][3][0];
        float ss = red[tid][0][1] + red[tid][1][1] + red[tid][2][1] + red[tid][3][1];
        float mu  = s * (1.0f / H_);
        float var = ss * (1.0f / H_) - mu * mu;
        mu_s[tid] = mu;
        rs_s[tid] = rsqrtf(var + 1e-5f);
    }
    __syncthreads();

    // ---- LN apply + ReLU -> hs ----
    {
        float4 gv = *(const float4*)(ga + j0);
        float4 bv = *(const float4*)(be + j0);
#pragma unroll
        for (int r = 0; r < R_; ++r) {
            float mu = mu_s[r], rs = rs_s[r];
            float4 hv;
            hv.x = gv.x * ((acc[r][0] - mu) * rs) + bv.x;
            hv.y = gv.y * ((acc[r][1] - mu) * rs) + bv.y;
            hv.z = gv.z * ((acc[r][2] - mu) * rs) + bv.z;
            hv.w = gv.w * ((acc[r][3] - mu) * rs) + bv.w;
            hv.x = hv.x > 0.f ? hv.x : 0.f;
            hv.y = hv.y > 0.f ? hv.y : 0.f;
            hv.z = hv.z > 0.f ? hv.z : 0.f;
            hv.w = hv.w > 0.f ? hv.w : 0.f;
            *(float4*)&hs[r][j0] = hv;
        }
    }
    __syncthreads();

    // ---- GEMM2: out[r][n] = [x,h][r] . w2[:, n] + b2[n] ----
    // wave handles rows wave*4..wave*4+3; lane owns contiguous j in [20*lane, 20*lane+20)
    float p[4][NOUT];
#pragma unroll
    for (int rr = 0; rr < 4; ++rr)
#pragma unroll
        for (int n = 0; n < NOUT; ++n) p[rr][n] = 0.f;

    const int jbase = lane * 20;
#pragma unroll
    for (int jj = 0; jj < 20; ++jj) {
        const int j = jbase + jj;
        float w2r[NOUT];
#pragma unroll
        for (int n = 0; n < NOUT; ++n) w2r[n] = w2[(size_t)j*NOUT + n];
#pragma unroll
        for (int rr = 0; rr < 4; ++rr) {
            const int r = wave*4 + rr;
            float v = (j < E_) ? xrow[r][j] : hs[r][j - E_];
#pragma unroll
            for (int n = 0; n < NOUT; ++n) p[rr][n] += v * w2r[n];
        }
    }
    // butterfly reduce across the wave (result lands in every lane)
#pragma unroll
    for (int rr = 0; rr < 4; ++rr)
#pragma unroll
        for (int n = 0; n < NOUT; ++n)
#pragma unroll
            for (int off = 32; off > 0; off >>= 1)
                p[rr][n] += __shfl_xor(p[rr][n], off, 64);

    if (lane == 0) {
#pragma unroll
        for (int rr = 0; rr < 4; ++rr) {
            const int r = wave*4 + rr;
            const int g = g0 + r;
#pragma unroll
            for (int n = 0; n < NOUT; ++n) {
                float v = p[rr][n] + b2[n];
                osh[r*NOUT + n] = v;
                gout[(size_t)g*NOUT + n] = v;
            }
        }
    }
    __syncthreads();
}

__global__ __launch_bounds__(256, 2)
void kp_fused(const float* __restrict__ hid,  const float* __restrict__ fkp,
              const float* __restrict__ w1ld, const float* __restrict__ b1ld,
              const float* __restrict__ gld,  const float* __restrict__ btld,
              const float* __restrict__ w2ld, const float* __restrict__ b2ld,
              const float* __restrict__ w1sd, const float* __restrict__ b1sd,
              const float* __restrict__ gsd,  const float* __restrict__ btsd,
              const float* __restrict__ w2sd, const float* __restrict__ b2sd,
              const int* __restrict__ ctx,
              float* __restrict__ out, float* __restrict__ ws)
{
    __shared__ float hs[R_][H_];        // 64 KB: post-LN hidden for GEMM2
    __shared__ float red[R_][4][2];     // cross-wave LN partials
    __shared__ float mu_s[R_], rs_s[R_];
    __shared__ float lo_s[R_*12];       // logits stash for epilogue
    __shared__ float sc_s[R_*6];        // scores stash for epilogue

    const int tid = threadIdx.x;
    const int g0  = blockIdx.x * R_;
    const int kp0 = ctx[0] - 1;

    const float* xrow[R_];
#pragma unroll
    for (int r = 0; r < R_; ++r) {
        const int g = g0 + r;
        const int b = g / T_;
        const int t = g - b * T_;
        xrow[r] = hid + (size_t)(b * S_ + kp0 + t) * E_;
    }

    decoder_phase<12>(xrow, w1ld, b1ld, gld, btld, w2ld, b2ld,
                      hs, red, mu_s, rs_s, lo_s, out + OFF_LOGITS, g0, tid);
    decoder_phase<6>(xrow, w1sd, b1sd, gsd, btsd, w2sd, b2sd,
                     hs, red, mu_s, rs_s, sc_s, out + OFF_SCORES, g0, tid);

    // ---- per-row loss epilogue ----
    if (tid < R_) {
        const int g = g0 + tid;
        const int b = g / T_;
        const int t = g - b * T_;
        const float y0 = fkp[b*(T_*2) + t*2 + 0];
        const float y1 = fkp[b*(T_*2) + t*2 + 1];

        float best = 1e30f; int am = 0;
#pragma unroll
        for (int k = 0; k < KK_; ++k) {
            float dx = lo_s[tid*12 + 2*k + 0] - y0;
            float dy = lo_s[tid*12 + 2*k + 1] - y1;
            float L = dx*dx + dy*dy;
            if (L < best) { best = L; am = k; }  // strict <: first-min like jnp.argmin
        }

        // softmax(scores) then log_softmax(softmax) (faithful double softmax)
        float m = -1e30f;
#pragma unroll
        for (int k = 0; k < KK_; ++k) m = fmaxf(m, sc_s[tid*6 + k]);
        float e[KK_]; float ssum = 0.f;
#pragma unroll
        for (int k = 0; k < KK_; ++k) { e[k] = expf(sc_s[tid*6 + k] - m); ssum += e[k]; }
        const float inv = 1.0f / ssum;
        float lse = 0.f, sm_am = 0.f;
#pragma unroll
        for (int k = 0; k < KK_; ++k) {
            float smk = e[k] * inv;
            lse += expf(smk);
            if (k == am) sm_am = smk;
        }
        const float ce = logf(lse) - sm_am;   // -(sm[am] - logsumexp(sm))

        out[OFF_SEL + g*2 + 0] = lo_s[tid*12 + 2*am + 0];
        out[OFF_SEL + g*2 + 1] = lo_s[tid*12 + 2*am + 1];

        atomicAdd(&ws[t],       best);  // sum over B of min_loss, per t
        atomicAdd(&ws[T_ + t],  ce);    // sum over B of ce, per t
    }
}

__global__ void kp_finalize(const float* __restrict__ ws, float* __restrict__ out)
{
    if (threadIdx.x == 0 && blockIdx.x == 0) {
        const float wts[T_] = {1e-4f, 1e-3f, 1e-2f, 1e-1f, 1.0f}; // 0.1^(4-t)
        float s = 0.f;
#pragma unroll
        for (int t = 0; t < T_; ++t) {
            float ml = ws[t]      * (1.0f / B_);
            float ce = ws[T_ + t] * (1.0f / B_);
            float l  = ml * wts[t] + ce;
            out[OFF_LPK + t] = l;
            s += l;
        }
        out[0] = s * (1.0f / T_);   // kp_loss (rescale = 1.0)
    }
}

extern "C" void kernel_launch(void* const* d_in, const int* in_sizes, int n_in,
                              void* d_out, int out_size, void* d_ws, size_t ws_size,
                              hipStream_t stream)
{
    const float* hid  = (const float*)d_in[0];
    const float* fkp  = (const float*)d_in[1];
    const float* w1ld = (const float*)d_in[2];
    const float* b1ld = (const float*)d_in[3];
    const float* gld  = (const float*)d_in[4];
    const float* btld = (const float*)d_in[5];
    const float* w2ld = (const float*)d_in[6];
    const float* b2ld = (const float*)d_in[7];
    const float* w1sd = (const float*)d_in[8];
    const float* b1sd = (const float*)d_in[9];
    const float* gsd  = (const float*)d_in[10];
    const float* btsd = (const float*)d_in[11];
    const float* w2sd = (const float*)d_in[12];
    const float* b2sd = (const float*)d_in[13];
    const int*   ctx  = (const int*)d_in[14];
    float* out = (float*)d_out;
    float* ws  = (float*)d_ws;

    // zero the 10 loss accumulators (ws is poisoned 0xAA before every launch)
    hipMemsetAsync(ws, 0, 2 * T_ * sizeof(float), stream);

    kp_fused<<<NBLK, 256, 0, stream>>>(hid, fkp,
                                       w1ld, b1ld, gld, btld, w2ld, b2ld,
                                       w1sd, b1sd, gsd, btsd, w2sd, b2sd,
                                       ctx, out, ws);
    kp_finalize<<<1, 64, 0, stream>>>(ws, out);
}

// Round 2
// 532.681 us; speedup vs baseline: 1.5438x; 1.5438x over previous
//
#include <hip/hip_runtime.h>
#include <math.h>

#define B_    2048
#define S_    134
#define E_    256
#define H_    1024
#define T_    5
#define KK_   6
#define NROWS (B_*T_)          // 10240
#define R_    8                // rows per block
#define NBLK  (NROWS/R_)       // 1280

// output layout (flat concat in return order)
#define OFF_LOGITS 1
#define OFF_SCORES (OFF_LOGITS + NROWS*12)   // 122881
#define OFF_SEL    (OFF_SCORES + NROWS*6)    // 184321
#define OFF_LPK    (OFF_SEL + NROWS*2)       // 204801

// One decoder phase: GEMM1 (x@w1+b1) -> LayerNorm -> ReLU -> GEMM2 ([x,h]@w2+b2)
// x comes from LDS (xs), h goes through LDS (hs). NOUT = 12 or 6.
template<int NOUT>
__device__ __forceinline__ void decoder_phase(
    const float (*xs)[E_],
    const float* __restrict__ w1, const float* __restrict__ b1,
    const float* __restrict__ ga, const float* __restrict__ be,
    const float* __restrict__ w2, const float* __restrict__ b2,
    float (*hs)[H_], float (*red)[4][2], float* mu_s, float* rs_s,
    float* osh, float* __restrict__ gout, int g0, int tid)
{
    const int wave = tid >> 6;
    const int lane = tid & 63;
    const int j0   = tid * 4;

    // ---- GEMM1: acc[r][c] = xs[r][:] . w1[:, j0+c] ----
    float acc[R_][4];
#pragma unroll
    for (int r = 0; r < R_; ++r) {
        acc[r][0] = 0.f; acc[r][1] = 0.f; acc[r][2] = 0.f; acc[r][3] = 0.f;
    }

    for (int k0 = 0; k0 < E_; k0 += 8) {
        // batch 8 coalesced float4 loads of w1 (8 VMEM in flight)
        float4 w[8];
#pragma unroll
        for (int kk = 0; kk < 8; ++kk)
            w[kk] = *(const float4*)(w1 + (size_t)(k0 + kk)*H_ + j0);
#pragma unroll
        for (int r = 0; r < R_; ++r) {
            float4 xa = *(const float4*)&xs[r][k0];     // wave-uniform -> LDS broadcast
            float4 xb = *(const float4*)&xs[r][k0+4];
            acc[r][0] += xa.x*w[0].x; acc[r][1] += xa.x*w[0].y; acc[r][2] += xa.x*w[0].z; acc[r][3] += xa.x*w[0].w;
            acc[r][0] += xa.y*w[1].x; acc[r][1] += xa.y*w[1].y; acc[r][2] += xa.y*w[1].z; acc[r][3] += xa.y*w[1].w;
            acc[r][0] += xa.z*w[2].x; acc[r][1] += xa.z*w[2].y; acc[r][2] += xa.z*w[2].z; acc[r][3] += xa.z*w[2].w;
            acc[r][0] += xa.w*w[3].x; acc[r][1] += xa.w*w[3].y; acc[r][2] += xa.w*w[3].z; acc[r][3] += xa.w*w[3].w;
            acc[r][0] += xb.x*w[4].x; acc[r][1] += xb.x*w[4].y; acc[r][2] += xb.x*w[4].z; acc[r][3] += xb.x*w[4].w;
            acc[r][0] += xb.y*w[5].x; acc[r][1] += xb.y*w[5].y; acc[r][2] += xb.y*w[5].z; acc[r][3] += xb.y*w[5].w;
            acc[r][0] += xb.z*w[6].x; acc[r][1] += xb.z*w[6].y; acc[r][2] += xb.z*w[6].z; acc[r][3] += xb.z*w[6].w;
            acc[r][0] += xb.w*w[7].x; acc[r][1] += xb.w*w[7].y; acc[r][2] += xb.w*w[7].z; acc[r][3] += xb.w*w[7].w;
        }
    }

    // bias
    {
        float4 bv = *(const float4*)(b1 + j0);
#pragma unroll
        for (int r = 0; r < R_; ++r) {
            acc[r][0] += bv.x; acc[r][1] += bv.y; acc[r][2] += bv.z; acc[r][3] += bv.w;
        }
    }

    // ---- LayerNorm stats: per-row sum / sumsq across 1024 cols ----
#pragma unroll
    for (int r = 0; r < R_; ++r) {
        float s  = acc[r][0] + acc[r][1] + acc[r][2] + acc[r][3];
        float ss = acc[r][0]*acc[r][0] + acc[r][1]*acc[r][1]
                 + acc[r][2]*acc[r][2] + acc[r][3]*acc[r][3];
#pragma unroll
        for (int off = 32; off > 0; off >>= 1) {
            s  += __shfl_xor(s,  off, 64);
            ss += __shfl_xor(ss, off, 64);
        }
        if (lane == 0) { red[r][wave][0] = s; red[r][wave][1] = ss; }
    }
    __syncthreads();
    if (tid < R_) {
        float s  = red[tid][0][0] + red[tid][1][0] + red[tid][2][0] + red[tid][3][0];
        float ss = red[tid][0][1] + red[tid][1][1] + red[tid][2][1] + red[tid][3][1];
        float mu  = s * (1.0f / H_);
        float var = ss * (1.0f / H_) - mu * mu;
        mu_s[tid] = mu;
        rs_s[tid] = rsqrtf(var + 1e-5f);
    }
    __syncthreads();

    // ---- LN apply + ReLU -> hs ----
    {
        float4 gv = *(const float4*)(ga + j0);
        float4 bv = *(const float4*)(be + j0);
#pragma unroll
        for (int r = 0; r < R_; ++r) {
            float mu = mu_s[r], rs = rs_s[r];
            float4 hv;
            hv.x = gv.x * ((acc[r][0] - mu) * rs) + bv.x;
            hv.y = gv.y * ((acc[r][1] - mu) * rs) + bv.y;
            hv.z = gv.z * ((acc[r][2] - mu) * rs) + bv.z;
            hv.w = gv.w * ((acc[r][3] - mu) * rs) + bv.w;
            hv.x = hv.x > 0.f ? hv.x : 0.f;
            hv.y = hv.y > 0.f ? hv.y : 0.f;
            hv.z = hv.z > 0.f ? hv.z : 0.f;
            hv.w = hv.w > 0.f ? hv.w : 0.f;
            *(float4*)&hs[r][j0] = hv;
        }
    }
    __syncthreads();

    // ---- GEMM2: out[r][n] = [x,h][r] . w2[:, n] + b2[n] ----
    // wave handles rows wave*2 .. wave*2+1; lane owns j in [20*lane, 20*lane+20)
    float p[2][NOUT];
#pragma unroll
    for (int rr = 0; rr < 2; ++rr)
#pragma unroll
        for (int n = 0; n < NOUT; ++n) p[rr][n] = 0.f;

    const int jbase = lane * 20;
#pragma unroll
    for (int jj = 0; jj < 20; ++jj) {
        const int j = jbase + jj;
        float w2r[NOUT];
#pragma unroll
        for (int n = 0; n < NOUT; ++n) w2r[n] = w2[(size_t)j*NOUT + n];
#pragma unroll
        for (int rr = 0; rr < 2; ++rr) {
            const int r = wave*2 + rr;
            float v = (j < E_) ? xs[r][j] : hs[r][j - E_];
#pragma unroll
            for (int n = 0; n < NOUT; ++n) p[rr][n] += v * w2r[n];
        }
    }
    // butterfly reduce across the wave
#pragma unroll
    for (int rr = 0; rr < 2; ++rr)
#pragma unroll
        for (int n = 0; n < NOUT; ++n)
#pragma unroll
            for (int off = 32; off > 0; off >>= 1)
                p[rr][n] += __shfl_xor(p[rr][n], off, 64);

    if (lane == 0) {
#pragma unroll
        for (int rr = 0; rr < 2; ++rr) {
            const int r = wave*2 + rr;
            const int g = g0 + r;
#pragma unroll
            for (int n = 0; n < NOUT; ++n) {
                float v = p[rr][n] + b2[n];
                osh[r*NOUT + n] = v;
                gout[(size_t)g*NOUT + n] = v;
            }
        }
    }
    __syncthreads();
}

__global__ __launch_bounds__(256, 3)
void kp_fused(const float* __restrict__ hid,  const float* __restrict__ fkp,
              const float* __restrict__ w1ld, const float* __restrict__ b1ld,
              const float* __restrict__ gld,  const float* __restrict__ btld,
              const float* __restrict__ w2ld, const float* __restrict__ b2ld,
              const float* __restrict__ w1sd, const float* __restrict__ b1sd,
              const float* __restrict__ gsd,  const float* __restrict__ btsd,
              const float* __restrict__ w2sd, const float* __restrict__ b2sd,
              const int* __restrict__ ctx,
              float* __restrict__ out, float* __restrict__ ws)
{
    __shared__ float hs[R_][H_];        // 32 KB: post-LN hidden for GEMM2
    __shared__ float xs[R_][E_];        // 8 KB: staged input rows
    __shared__ float red[R_][4][2];     // cross-wave LN partials
    __shared__ float mu_s[R_], rs_s[R_];
    __shared__ float lo_s[R_*12];       // logits stash for epilogue
    __shared__ float sc_s[R_*6];        // scores stash for epilogue

    const int tid = threadIdx.x;
    const int g0  = blockIdx.x * R_;
    const int kp0 = ctx[0] - 1;

    // ---- stage x rows into LDS (coalesced): thread t -> row t>>5, floats (t&31)*8 .. +7
    {
        const int r   = tid >> 5;
        const int off = (tid & 31) * 8;
        const int g = g0 + r;
        const int b = g / T_;
        const int t = g - b * T_;
        const float* src = hid + (size_t)(b * S_ + kp0 + t) * E_ + off;
        float4 v0 = *(const float4*)(src);
        float4 v1 = *(const float4*)(src + 4);
        *(float4*)&xs[r][off]     = v0;
        *(float4*)&xs[r][off + 4] = v1;
    }
    __syncthreads();

    decoder_phase<12>(xs, w1ld, b1ld, gld, btld, w2ld, b2ld,
                      hs, red, mu_s, rs_s, lo_s, out + OFF_LOGITS, g0, tid);
    decoder_phase<6>(xs, w1sd, b1sd, gsd, btsd, w2sd, b2sd,
                     hs, red, mu_s, rs_s, sc_s, out + OFF_SCORES, g0, tid);

    // ---- per-row loss epilogue ----
    if (tid < R_) {
        const int g = g0 + tid;
        const int b = g / T_;
        const int t = g - b * T_;
        const float y0 = fkp[b*(T_*2) + t*2 + 0];
        const float y1 = fkp[b*(T_*2) + t*2 + 1];

        float best = 1e30f; int am = 0;
#pragma unroll
        for (int k = 0; k < KK_; ++k) {
            float dx = lo_s[tid*12 + 2*k + 0] - y0;
            float dy = lo_s[tid*12 + 2*k + 1] - y1;
            float L = dx*dx + dy*dy;
            if (L < best) { best = L; am = k; }  // strict <: first-min like jnp.argmin
        }

        // softmax(scores) then log_softmax(softmax) (faithful double softmax)
        float m = -1e30f;
#pragma unroll
        for (int k = 0; k < KK_; ++k) m = fmaxf(m, sc_s[tid*6 + k]);
        float e[KK_]; float ssum = 0.f;
#pragma unroll
        for (int k = 0; k < KK_; ++k) { e[k] = expf(sc_s[tid*6 + k] - m); ssum += e[k]; }
        const float inv = 1.0f / ssum;
        float lse = 0.f, sm_am = 0.f;
#pragma unroll
        for (int k = 0; k < KK_; ++k) {
            float smk = e[k] * inv;
            lse += expf(smk);
            if (k == am) sm_am = smk;
        }
        const float ce = logf(lse) - sm_am;   // -(sm[am] - logsumexp(sm))

        out[OFF_SEL + g*2 + 0] = lo_s[tid*12 + 2*am + 0];
        out[OFF_SEL + g*2 + 1] = lo_s[tid*12 + 2*am + 1];

        atomicAdd(&ws[t],       best);  // sum over B of min_loss, per t
        atomicAdd(&ws[T_ + t],  ce);    // sum over B of ce, per t
    }
}

__global__ void kp_finalize(const float* __restrict__ ws, float* __restrict__ out)
{
    if (threadIdx.x == 0 && blockIdx.x == 0) {
        const float wts[T_] = {1e-4f, 1e-3f, 1e-2f, 1e-1f, 1.0f}; // 0.1^(4-t)
        float s = 0.f;
#pragma unroll
        for (int t = 0; t < T_; ++t) {
            float ml = ws[t]      * (1.0f / B_);
            float ce = ws[T_ + t] * (1.0f / B_);
            float l  = ml * wts[t] + ce;
            out[OFF_LPK + t] = l;
            s += l;
        }
        out[0] = s * (1.0f / T_);   // kp_loss (rescale = 1.0)
    }
}

extern "C" void kernel_launch(void* const* d_in, const int* in_sizes, int n_in,
                              void* d_out, int out_size, void* d_ws, size_t ws_size,
                              hipStream_t stream)
{
    const float* hid  = (const float*)d_in[0];
    const float* fkp  = (const float*)d_in[1];
    const float* w1ld = (const float*)d_in[2];
    const float* b1ld = (const float*)d_in[3];
    const float* gld  = (const float*)d_in[4];
    const float* btld = (const float*)d_in[5];
    const float* w2ld = (const float*)d_in[6];
    const float* b2ld = (const float*)d_in[7];
    const float* w1sd = (const float*)d_in[8];
    const float* b1sd = (const float*)d_in[9];
    const float* gsd  = (const float*)d_in[10];
    const float* btsd = (const float*)d_in[11];
    const float* w2sd = (const float*)d_in[12];
    const float* b2sd = (const float*)d_in[13];
    const int*   ctx  = (const int*)d_in[14];
    float* out = (float*)d_out;
    float* ws  = (float*)d_ws;

    // zero the 10 loss accumulators (ws is poisoned 0xAA before every launch)
    hipMemsetAsync(ws, 0, 2 * T_ * sizeof(float), stream);

    kp_fused<<<NBLK, 256, 0, stream>>>(hid, fkp,
                                       w1ld, b1ld, gld, btld, w2ld, b2ld,
                                       w1sd, b1sd, gsd, btsd, w2sd, b2sd,
                                       ctx, out, ws);
    kp_finalize<<<1, 64, 0, stream>>>(ws, out);
}